// Round 1
// baseline (2609.646 us; speedup 1.0000x reference)
//
#include <hip/hip_runtime.h>
#include <hip/hip_bf16.h>

#define NE 8
#define HID 2048
#define INTER 5504
#define TOK 16384
#define TE 2048  // tokens per expert

typedef __bf16 bf16x8 __attribute__((ext_vector_type(8)));
typedef float f32x4 __attribute__((ext_vector_type(4)));

__device__ __forceinline__ void async_copy16(const void* g, void* l) {
    __builtin_amdgcn_global_load_lds(
        (const __attribute__((address_space(1))) void*)g,
        (__attribute__((address_space(3))) void*)l,
        16, 0, 0);
}

// ---------------- cast x: fp32 -> bf16, vectorized ----------------
struct alignas(8) bf4 { __hip_bfloat162 a, b; };

__global__ void cast_x_kernel(const float* __restrict__ in, __hip_bfloat16* __restrict__ out) {
    size_t i = (size_t)blockIdx.x * blockDim.x + threadIdx.x;  // one float4 per thread
    float4 v = reinterpret_cast<const float4*>(in)[i];
    bf4 p;
    p.a.x = __float2bfloat16(v.x);
    p.a.y = __float2bfloat16(v.y);
    p.b.x = __float2bfloat16(v.z);
    p.b.y = __float2bfloat16(v.w);
    reinterpret_cast<bf4*>(out)[i] = p;
}

// ---------------- transpose + cast: fp32 [E][R][C] -> bf16 [E][C][R] ----------------
__global__ void tcast_kernel(const float* __restrict__ in, __hip_bfloat16* __restrict__ out,
                             int R, int C) {
    __shared__ float tile[32][33];
    const int e = blockIdx.z;
    const int r0 = blockIdx.y * 32, c0 = blockIdx.x * 32;
    const float* src = in + (size_t)e * R * C;
    __hip_bfloat16* dst = out + (size_t)e * R * C;
    const int tx = threadIdx.x;  // 0..31
    const int ty = threadIdx.y;  // 0..7
#pragma unroll
    for (int i = 0; i < 32; i += 8)
        tile[ty + i][tx] = src[(size_t)(r0 + ty + i) * C + (c0 + tx)];
    __syncthreads();
#pragma unroll
    for (int i = 0; i < 32; i += 8)
        dst[(size_t)(c0 + ty + i) * R + (r0 + tx)] = __float2bfloat16(tile[tx][ty + i]);
}

// ---------------- GEMM1: x @ {gate,up} fused + SwiGLU -> h (bf16) ----------------
// A: xb [TOK][HID] bf16.  Bg/Bu: [E][INTER][HID] bf16 (transposed weights, k-contiguous).
// Output h: [TOK][INTER] bf16.
// 128x128 tile, BK=32, 256 threads (4 waves 2x2), 16x16x32 bf16 MFMA.
__global__ __launch_bounds__(256, 2) void gemm1_swiglu_kernel(
    const __hip_bfloat16* __restrict__ xb,
    const __hip_bfloat16* __restrict__ gwt,
    const __hip_bfloat16* __restrict__ uwt,
    __hip_bfloat16* __restrict__ hout) {
    const int e = blockIdx.z;
    const int mt = blockIdx.y;  // 0..15
    const int nt = blockIdx.x;  // 0..42
    const int m0 = mt * 128;
    const int n0 = nt * 128;

    const __hip_bfloat16* A = xb + (size_t)(e * TE + m0) * HID;
    const __hip_bfloat16* Bg = gwt + (size_t)e * INTER * HID + (size_t)n0 * HID;
    const __hip_bfloat16* Bu = uwt + (size_t)e * INTER * HID + (size_t)n0 * HID;

    __shared__ __align__(16) __hip_bfloat16 As[128 * 32];
    __shared__ __align__(16) __hip_bfloat16 Bgs[128 * 32];
    __shared__ __align__(16) __hip_bfloat16 Bus[128 * 32];

    const int tid = threadIdx.x;
    const int wave = tid >> 6, lane = tid & 63;
    const int ch0 = wave * 128 + lane;  // 16B-chunk id (of 512), +64 for second

    const int wm = (wave >> 1) * 64;  // wave row offset in 128-tile
    const int wn = (wave & 1) * 64;
    const int qd = lane >> 4;   // 0..3
    const int ln = lane & 15;

    f32x4 accg[4][4], accu[4][4];
    const f32x4 z4 = {0.f, 0.f, 0.f, 0.f};
#pragma unroll
    for (int mi = 0; mi < 4; ++mi)
#pragma unroll
        for (int ni = 0; ni < 4; ++ni) { accg[mi][ni] = z4; accu[mi][ni] = z4; }

    for (int kk = 0; kk < HID; kk += 32) {
#pragma unroll
        for (int i = 0; i < 2; ++i) {
            const int c = ch0 + i * 64;
            const int row = c >> 2;
            const int col = (c & 3) * 8;
            async_copy16(A + (size_t)row * HID + kk + col, (void*)(As + c * 8));
            async_copy16(Bg + (size_t)row * HID + kk + col, (void*)(Bgs + c * 8));
            async_copy16(Bu + (size_t)row * HID + kk + col, (void*)(Bus + c * 8));
        }
        __syncthreads();

        bf16x8 af[4], bgf[4], buf_[4];
#pragma unroll
        for (int mi = 0; mi < 4; ++mi)
            af[mi] = *reinterpret_cast<const bf16x8*>(As + (wm + mi * 16 + ln) * 32 + qd * 8);
#pragma unroll
        for (int ni = 0; ni < 4; ++ni) {
            bgf[ni] = *reinterpret_cast<const bf16x8*>(Bgs + (wn + ni * 16 + ln) * 32 + qd * 8);
            buf_[ni] = *reinterpret_cast<const bf16x8*>(Bus + (wn + ni * 16 + ln) * 32 + qd * 8);
        }
#pragma unroll
        for (int mi = 0; mi < 4; ++mi)
#pragma unroll
            for (int ni = 0; ni < 4; ++ni) {
                accg[mi][ni] = __builtin_amdgcn_mfma_f32_16x16x32_bf16(af[mi], bgf[ni], accg[mi][ni], 0, 0, 0);
                accu[mi][ni] = __builtin_amdgcn_mfma_f32_16x16x32_bf16(af[mi], buf_[ni], accu[mi][ni], 0, 0, 0);
            }
        __syncthreads();
    }

    // epilogue: SwiGLU, write bf16 h.  C/D layout: col=lane&15, row=(lane>>4)*4+r
    __hip_bfloat16* Hbase = hout + (size_t)(e * TE + m0) * INTER + n0;
#pragma unroll
    for (int mi = 0; mi < 4; ++mi)
#pragma unroll
        for (int ni = 0; ni < 4; ++ni)
#pragma unroll
            for (int r = 0; r < 4; ++r) {
                const int rr = wm + mi * 16 + qd * 4 + r;
                const int cc = wn + ni * 16 + ln;
                const float g = accg[mi][ni][r];
                const float u = accu[mi][ni][r];
                const float s = g / (1.0f + __expf(-g));
                Hbase[(size_t)rr * INTER + cc] = __float2bfloat16(s * u);
            }
}

// ---------------- GEMM2: h @ down -> out (fp32) ----------------
// A: h [TOK][INTER] bf16.  B: dwt [E][HID][INTER] bf16 (transposed down_w).
__global__ __launch_bounds__(256, 2) void gemm2_kernel(
    const __hip_bfloat16* __restrict__ hb,
    const __hip_bfloat16* __restrict__ dwt,
    float* __restrict__ out) {
    const int e = blockIdx.z;
    const int mt = blockIdx.y;  // 0..15
    const int nt = blockIdx.x;  // 0..15
    const int m0 = mt * 128;
    const int n0 = nt * 128;

    const __hip_bfloat16* A = hb + (size_t)(e * TE + m0) * INTER;
    const __hip_bfloat16* B = dwt + (size_t)e * HID * INTER + (size_t)n0 * INTER;

    __shared__ __align__(16) __hip_bfloat16 As[128 * 32];
    __shared__ __align__(16) __hip_bfloat16 Bs[128 * 32];

    const int tid = threadIdx.x;
    const int wave = tid >> 6, lane = tid & 63;
    const int ch0 = wave * 128 + lane;

    const int wm = (wave >> 1) * 64;
    const int wn = (wave & 1) * 64;
    const int qd = lane >> 4;
    const int ln = lane & 15;

    f32x4 acc[4][4];
    const f32x4 z4 = {0.f, 0.f, 0.f, 0.f};
#pragma unroll
    for (int mi = 0; mi < 4; ++mi)
#pragma unroll
        for (int ni = 0; ni < 4; ++ni) acc[mi][ni] = z4;

    for (int kk = 0; kk < INTER; kk += 32) {
#pragma unroll
        for (int i = 0; i < 2; ++i) {
            const int c = ch0 + i * 64;
            const int row = c >> 2;
            const int col = (c & 3) * 8;
            async_copy16(A + (size_t)row * INTER + kk + col, (void*)(As + c * 8));
            async_copy16(B + (size_t)row * INTER + kk + col, (void*)(Bs + c * 8));
        }
        __syncthreads();

        bf16x8 af[4], bf_[4];
#pragma unroll
        for (int mi = 0; mi < 4; ++mi)
            af[mi] = *reinterpret_cast<const bf16x8*>(As + (wm + mi * 16 + ln) * 32 + qd * 8);
#pragma unroll
        for (int ni = 0; ni < 4; ++ni)
            bf_[ni] = *reinterpret_cast<const bf16x8*>(Bs + (wn + ni * 16 + ln) * 32 + qd * 8);
#pragma unroll
        for (int mi = 0; mi < 4; ++mi)
#pragma unroll
            for (int ni = 0; ni < 4; ++ni)
                acc[mi][ni] = __builtin_amdgcn_mfma_f32_16x16x32_bf16(af[mi], bf_[ni], acc[mi][ni], 0, 0, 0);
        __syncthreads();
    }

    float* Obase = out + (size_t)(e * TE + m0) * HID + n0;
#pragma unroll
    for (int mi = 0; mi < 4; ++mi)
#pragma unroll
        for (int ni = 0; ni < 4; ++ni)
#pragma unroll
            for (int r = 0; r < 4; ++r) {
                const int rr = wm + mi * 16 + qd * 4 + r;
                const int cc = wn + ni * 16 + ln;
                Obase[(size_t)rr * HID + cc] = acc[mi][ni][r];
            }
}

extern "C" void kernel_launch(void* const* d_in, const int* in_sizes, int n_in,
                              void* d_out, int out_size, void* d_ws, size_t ws_size,
                              hipStream_t stream) {
    const float* x = (const float*)d_in[0];
    const float* gw = (const float*)d_in[1];   // [E][HID][INTER]
    const float* uw = (const float*)d_in[2];   // [E][HID][INTER]
    const float* dw = (const float*)d_in[3];   // [E][INTER][HID]
    float* out = (float*)d_out;

    // workspace layout (bytes)
    const size_t XB_BYTES = (size_t)TOK * HID * 2;           // 67,108,864
    const size_t WT_BYTES = (size_t)NE * INTER * HID * 2;    // 180,355,072
    char* ws = (char*)d_ws;
    __hip_bfloat16* xb = (__hip_bfloat16*)(ws);
    __hip_bfloat16* gwt = (__hip_bfloat16*)(ws + XB_BYTES);
    __hip_bfloat16* uwt = (__hip_bfloat16*)(ws + XB_BYTES + WT_BYTES);
    __hip_bfloat16* hb = (__hip_bfloat16*)(ws + XB_BYTES + 2 * WT_BYTES);
    __hip_bfloat16* dwt = gwt;  // alias: down_w transposed after gemm1 consumed gwt

    // 1) cast x -> bf16
    cast_x_kernel<<<(TOK * HID) / (256 * 4), 256, 0, stream>>>(x, xb);
    // 2) transpose+cast gate/up: [HID][INTER] -> [INTER][HID]
    tcast_kernel<<<dim3(INTER / 32, HID / 32, NE), dim3(32, 8), 0, stream>>>(gw, gwt, HID, INTER);
    tcast_kernel<<<dim3(INTER / 32, HID / 32, NE), dim3(32, 8), 0, stream>>>(uw, uwt, HID, INTER);
    // 3) fused gate/up GEMM + SwiGLU -> h
    gemm1_swiglu_kernel<<<dim3(INTER / 128, TE / 128, NE), 256, 0, stream>>>(xb, gwt, uwt, hb);
    // 4) transpose+cast down: [INTER][HID] -> [HID][INTER] (into gwt region)
    tcast_kernel<<<dim3(HID / 32, INTER / 32, NE), dim3(32, 8), 0, stream>>>(dw, dwt, INTER, HID);
    // 5) down GEMM -> fp32 out
    gemm2_kernel<<<dim3(HID / 128, TE / 128, NE), 256, 0, stream>>>(hb, dwt, out);
}

// Round 2
// 2454.378 us; speedup vs baseline: 1.0633x; 1.0633x over previous
//
#include <hip/hip_runtime.h>
#include <hip/hip_bf16.h>

#define NE 8
#define HID 2048
#define INTER 5504
#define TOK 16384
#define TE 2048  // tokens per expert

typedef __bf16 bf16x8 __attribute__((ext_vector_type(8)));
typedef float f32x4 __attribute__((ext_vector_type(4)));

__device__ __forceinline__ void async_copy16(const void* g, void* l) {
    __builtin_amdgcn_global_load_lds(
        (const __attribute__((address_space(1))) void*)g,
        (__attribute__((address_space(3))) void*)l,
        16, 0, 0);
}

// XOR swizzle on 16B-chunk index: involutive (key bits 3..5 unchanged by xor of bits 0..2).
// Breaks the 8-way LDS bank conflict of the 64B-row-stride fragment reads down to 2-way (free).
__device__ __forceinline__ int chunk_swz(int q) { return q ^ ((q >> 3) & 7); }

// ---------------- cast x: fp32 -> bf16, vectorized ----------------
struct alignas(8) bf4 { __hip_bfloat162 a, b; };

__global__ void cast_x_kernel(const float* __restrict__ in, __hip_bfloat16* __restrict__ out) {
    size_t i = (size_t)blockIdx.x * blockDim.x + threadIdx.x;  // one float4 per thread
    float4 v = reinterpret_cast<const float4*>(in)[i];
    bf4 p;
    p.a.x = __float2bfloat16(v.x);
    p.a.y = __float2bfloat16(v.y);
    p.b.x = __float2bfloat16(v.z);
    p.b.y = __float2bfloat16(v.w);
    reinterpret_cast<bf4*>(out)[i] = p;
}

// ---------------- transpose + cast: fp32 [E][R][C] -> bf16 [E][C][R] ----------------
__global__ void tcast_kernel(const float* __restrict__ in, __hip_bfloat16* __restrict__ out,
                             int R, int C) {
    __shared__ float tile[32][33];
    const int e = blockIdx.z;
    const int r0 = blockIdx.y * 32, c0 = blockIdx.x * 32;
    const float* src = in + (size_t)e * R * C;
    __hip_bfloat16* dst = out + (size_t)e * R * C;
    const int tx = threadIdx.x;  // 0..31
    const int ty = threadIdx.y;  // 0..7
#pragma unroll
    for (int i = 0; i < 32; i += 8)
        tile[ty + i][tx] = src[(size_t)(r0 + ty + i) * C + (c0 + tx)];
    __syncthreads();
#pragma unroll
    for (int i = 0; i < 32; i += 8)
        dst[(size_t)(c0 + ty + i) * R + (r0 + tx)] = __float2bfloat16(tile[tx][ty + i]);
}

// ---------------- GEMM1: x @ {gate,up} fused + SwiGLU -> h (bf16) ----------------
// A: xb [TOK][HID] bf16.  Bg/Bu: [E][INTER][HID] bf16 (transposed weights, k-contiguous).
// Output h: [TOK][INTER] bf16.
// 128x128 tile, BK=32, 256 threads (4 waves 2x2), 16x16x32 bf16 MFMA.
// Grid: x = m-tile (fastest) so co-resident blocks share B weight tiles -> L2-resident.
__global__ __launch_bounds__(256, 2) void gemm1_swiglu_kernel(
    const __hip_bfloat16* __restrict__ xb,
    const __hip_bfloat16* __restrict__ gwt,
    const __hip_bfloat16* __restrict__ uwt,
    __hip_bfloat16* __restrict__ hout) {
    const int e = blockIdx.z;
    const int mt = blockIdx.x;  // 0..15 (fastest -> 256 co-resident blocks = 1 expert slab)
    const int nt = blockIdx.y;  // 0..42
    const int m0 = mt * 128;
    const int n0 = nt * 128;

    const __hip_bfloat16* A = xb + (size_t)(e * TE + m0) * HID;
    const __hip_bfloat16* Bg = gwt + (size_t)e * INTER * HID + (size_t)n0 * HID;
    const __hip_bfloat16* Bu = uwt + (size_t)e * INTER * HID + (size_t)n0 * HID;

    __shared__ __align__(16) __hip_bfloat16 As[128 * 32];
    __shared__ __align__(16) __hip_bfloat16 Bgs[128 * 32];
    __shared__ __align__(16) __hip_bfloat16 Bus[128 * 32];

    const int tid = threadIdx.x;
    const int wave = tid >> 6, lane = tid & 63;
    const int ch0 = wave * 128 + lane;  // physical 16B-chunk id (of 512), +64 for second

    const int wm = (wave >> 1) * 64;  // wave row offset in 128-tile
    const int wn = (wave & 1) * 64;
    const int qd = lane >> 4;   // 0..3
    const int ln = lane & 15;

    f32x4 accg[4][4], accu[4][4];
    const f32x4 z4 = {0.f, 0.f, 0.f, 0.f};
#pragma unroll
    for (int mi = 0; mi < 4; ++mi)
#pragma unroll
        for (int ni = 0; ni < 4; ++ni) { accg[mi][ni] = z4; accu[mi][ni] = z4; }

    for (int kk = 0; kk < HID; kk += 32) {
#pragma unroll
        for (int i = 0; i < 2; ++i) {
            const int c = ch0 + i * 64;       // physical chunk this lane fills
            const int id = chunk_swz(c);      // logical (row,col) it should hold
            const int row = id >> 2;
            const int col = (id & 3) * 8;
            async_copy16(A + (size_t)row * HID + kk + col, (void*)(As + c * 8));
            async_copy16(Bg + (size_t)row * HID + kk + col, (void*)(Bgs + c * 8));
            async_copy16(Bu + (size_t)row * HID + kk + col, (void*)(Bus + c * 8));
        }
        __syncthreads();

        bf16x8 af[4], bgf[4], buf_[4];
#pragma unroll
        for (int mi = 0; mi < 4; ++mi) {
            const int p = chunk_swz((wm + mi * 16 + ln) * 4 + qd);
            af[mi] = *reinterpret_cast<const bf16x8*>(As + p * 8);
        }
#pragma unroll
        for (int ni = 0; ni < 4; ++ni) {
            const int p = chunk_swz((wn + ni * 16 + ln) * 4 + qd);
            bgf[ni] = *reinterpret_cast<const bf16x8*>(Bgs + p * 8);
            buf_[ni] = *reinterpret_cast<const bf16x8*>(Bus + p * 8);
        }
#pragma unroll
        for (int mi = 0; mi < 4; ++mi)
#pragma unroll
            for (int ni = 0; ni < 4; ++ni) {
                accg[mi][ni] = __builtin_amdgcn_mfma_f32_16x16x32_bf16(af[mi], bgf[ni], accg[mi][ni], 0, 0, 0);
                accu[mi][ni] = __builtin_amdgcn_mfma_f32_16x16x32_bf16(af[mi], buf_[ni], accu[mi][ni], 0, 0, 0);
            }
        __syncthreads();
    }

    // epilogue: SwiGLU, write bf16 h.  C/D layout: col=lane&15, row=(lane>>4)*4+r
    __hip_bfloat16* Hbase = hout + (size_t)(e * TE + m0) * INTER + n0;
#pragma unroll
    for (int mi = 0; mi < 4; ++mi)
#pragma unroll
        for (int ni = 0; ni < 4; ++ni)
#pragma unroll
            for (int r = 0; r < 4; ++r) {
                const int rr = wm + mi * 16 + qd * 4 + r;
                const int cc = wn + ni * 16 + ln;
                const float g = accg[mi][ni][r];
                const float u = accu[mi][ni][r];
                const float s = g / (1.0f + __expf(-g));
                Hbase[(size_t)rr * INTER + cc] = __float2bfloat16(s * u);
            }
}

// ---------------- GEMM2: h @ down -> out (fp32) ----------------
// A: h [TOK][INTER] bf16.  B: dwt [E][HID][INTER] bf16 (transposed down_w).
__global__ __launch_bounds__(256, 2) void gemm2_kernel(
    const __hip_bfloat16* __restrict__ hb,
    const __hip_bfloat16* __restrict__ dwt,
    float* __restrict__ out) {
    const int e = blockIdx.z;
    const int mt = blockIdx.x;  // 0..15 (fastest)
    const int nt = blockIdx.y;  // 0..15
    const int m0 = mt * 128;
    const int n0 = nt * 128;

    const __hip_bfloat16* A = hb + (size_t)(e * TE + m0) * INTER;
    const __hip_bfloat16* B = dwt + (size_t)e * HID * INTER + (size_t)n0 * INTER;

    __shared__ __align__(16) __hip_bfloat16 As[128 * 32];
    __shared__ __align__(16) __hip_bfloat16 Bs[128 * 32];

    const int tid = threadIdx.x;
    const int wave = tid >> 6, lane = tid & 63;
    const int ch0 = wave * 128 + lane;

    const int wm = (wave >> 1) * 64;
    const int wn = (wave & 1) * 64;
    const int qd = lane >> 4;
    const int ln = lane & 15;

    f32x4 acc[4][4];
    const f32x4 z4 = {0.f, 0.f, 0.f, 0.f};
#pragma unroll
    for (int mi = 0; mi < 4; ++mi)
#pragma unroll
        for (int ni = 0; ni < 4; ++ni) acc[mi][ni] = z4;

    for (int kk = 0; kk < INTER; kk += 32) {
#pragma unroll
        for (int i = 0; i < 2; ++i) {
            const int c = ch0 + i * 64;
            const int id = chunk_swz(c);
            const int row = id >> 2;
            const int col = (id & 3) * 8;
            async_copy16(A + (size_t)row * INTER + kk + col, (void*)(As + c * 8));
            async_copy16(B + (size_t)row * INTER + kk + col, (void*)(Bs + c * 8));
        }
        __syncthreads();

        bf16x8 af[4], bf_[4];
#pragma unroll
        for (int mi = 0; mi < 4; ++mi) {
            const int p = chunk_swz((wm + mi * 16 + ln) * 4 + qd);
            af[mi] = *reinterpret_cast<const bf16x8*>(As + p * 8);
        }
#pragma unroll
        for (int ni = 0; ni < 4; ++ni) {
            const int p = chunk_swz((wn + ni * 16 + ln) * 4 + qd);
            bf_[ni] = *reinterpret_cast<const bf16x8*>(Bs + p * 8);
        }
#pragma unroll
        for (int mi = 0; mi < 4; ++mi)
#pragma unroll
            for (int ni = 0; ni < 4; ++ni)
                acc[mi][ni] = __builtin_amdgcn_mfma_f32_16x16x32_bf16(af[mi], bf_[ni], acc[mi][ni], 0, 0, 0);
        __syncthreads();
    }

    float* Obase = out + (size_t)(e * TE + m0) * HID + n0;
#pragma unroll
    for (int mi = 0; mi < 4; ++mi)
#pragma unroll
        for (int ni = 0; ni < 4; ++ni)
#pragma unroll
            for (int r = 0; r < 4; ++r) {
                const int rr = wm + mi * 16 + qd * 4 + r;
                const int cc = wn + ni * 16 + ln;
                Obase[(size_t)rr * HID + cc] = acc[mi][ni][r];
            }
}

extern "C" void kernel_launch(void* const* d_in, const int* in_sizes, int n_in,
                              void* d_out, int out_size, void* d_ws, size_t ws_size,
                              hipStream_t stream) {
    const float* x = (const float*)d_in[0];
    const float* gw = (const float*)d_in[1];   // [E][HID][INTER]
    const float* uw = (const float*)d_in[2];   // [E][HID][INTER]
    const float* dw = (const float*)d_in[3];   // [E][INTER][HID]
    float* out = (float*)d_out;

    // workspace layout (bytes)
    const size_t XB_BYTES = (size_t)TOK * HID * 2;           // 67,108,864
    const size_t WT_BYTES = (size_t)NE * INTER * HID * 2;    // 180,355,072
    char* ws = (char*)d_ws;
    __hip_bfloat16* xb = (__hip_bfloat16*)(ws);
    __hip_bfloat16* gwt = (__hip_bfloat16*)(ws + XB_BYTES);
    __hip_bfloat16* uwt = (__hip_bfloat16*)(ws + XB_BYTES + WT_BYTES);
    __hip_bfloat16* hb = (__hip_bfloat16*)(ws + XB_BYTES + 2 * WT_BYTES);
    __hip_bfloat16* dwt = gwt;  // alias: down_w transposed after gemm1 consumed gwt

    // 1) cast x -> bf16
    cast_x_kernel<<<(TOK * HID) / (256 * 4), 256, 0, stream>>>(x, xb);
    // 2) transpose+cast gate/up: [HID][INTER] -> [INTER][HID]
    tcast_kernel<<<dim3(INTER / 32, HID / 32, NE), dim3(32, 8), 0, stream>>>(gw, gwt, HID, INTER);
    tcast_kernel<<<dim3(INTER / 32, HID / 32, NE), dim3(32, 8), 0, stream>>>(uw, uwt, HID, INTER);
    // 3) fused gate/up GEMM + SwiGLU -> h   (m-tile fastest for B-tile L2 residency)
    gemm1_swiglu_kernel<<<dim3(TE / 128, INTER / 128, NE), 256, 0, stream>>>(xb, gwt, uwt, hb);
    // 4) transpose+cast down: [INTER][HID] -> [HID][INTER] (into gwt region)
    tcast_kernel<<<dim3(HID / 32, INTER / 32, NE), dim3(32, 8), 0, stream>>>(dw, dwt, INTER, HID);
    // 5) down GEMM -> fp32 out
    gemm2_kernel<<<dim3(TE / 128, HID / 128, NE), 256, 0, stream>>>(hb, dwt, out);
}